// Round 3
// baseline (301.387 us; speedup 1.0000x reference)
//
#include <hip/hip_runtime.h>
#include <hip/hip_bf16.h>

typedef __attribute__((ext_vector_type(8))) short s16x8;
typedef __attribute__((ext_vector_type(4))) float f32x4;

__device__ __forceinline__ unsigned short f2b(float x) {
  unsigned int u = __float_as_uint(x);
  u = (u + 0x7fffu + ((u >> 16) & 1u)) >> 16;
  return (unsigned short)u;
}

__device__ __forceinline__ unsigned int pkbf(float a, float b) {
  return (unsigned int)f2b(a) | ((unsigned int)f2b(b) << 16);
}

__device__ __forceinline__ float b2f(unsigned short u) {
  return __uint_as_float((unsigned int)u << 16);
}

// ---------------------------------------------------------------- cast fp32 -> bf16
__global__ void cast_kernel(const float* __restrict__ in, unsigned short* __restrict__ out, int n4) {
  int i = blockIdx.x * blockDim.x + threadIdx.x;
  if (i < n4) {
    const float4 v = ((const float4*)in)[i];
    ushort4 o;
    o.x = f2b(v.x); o.y = f2b(v.y); o.z = f2b(v.z); o.w = f2b(v.w);
    ((ushort4*)out)[i] = o;
  }
}

#define BM 128
#define BN 128
#define BK 64
#define LDA 72
#define KDIM 1024

// ---------------------------------------------------------------- QKV GEMM + fused RoPE
__global__ __launch_bounds__(256) void gemm_qkv(
    const unsigned short* __restrict__ A,
    const unsigned short* __restrict__ Bt,
    const int* __restrict__ tok,
    unsigned short* __restrict__ Qo,
    unsigned short* __restrict__ Ko,
    unsigned short* __restrict__ Vt) {
  __shared__ unsigned short As[BM * LDA];
  __shared__ unsigned short Bs[BN * LDA];
  const int tid = threadIdx.x;
  const int m0 = blockIdx.x * BM;
  const int n0 = blockIdx.y * BN;
  const int w = tid >> 6, lane = tid & 63;
  const int ln = lane & 15, quad = lane >> 4;
  const int wm = (w >> 1) * 64, wn = (w & 1) * 64;

  const f32x4 zero = {0.f, 0.f, 0.f, 0.f};
  f32x4 acc[4][4];
#pragma unroll
  for (int i = 0; i < 4; ++i)
#pragma unroll
    for (int j = 0; j < 4; ++j) acc[i][j] = zero;

  for (int kb = 0; kb < KDIM / BK; ++kb) {
#pragma unroll
    for (int it = 0; it < 4; ++it) {
      int c = tid + it * 256;
      int row = c >> 3;
      int col = (c & 7) << 3;
      *(uint4*)(&As[row * LDA + col]) = *(const uint4*)(&A[(size_t)(m0 + row) * KDIM + kb * BK + col]);
      *(uint4*)(&Bs[row * LDA + col]) = *(const uint4*)(&Bt[(size_t)(n0 + row) * KDIM + kb * BK + col]);
    }
    __syncthreads();
#pragma unroll
    for (int ks = 0; ks < 2; ++ks) {
      s16x8 af[4], bfr[4];
#pragma unroll
      for (int i = 0; i < 4; ++i)
        af[i] = *(const s16x8*)(&As[(wm + i * 16 + ln) * LDA + ks * 32 + quad * 8]);
#pragma unroll
      for (int j = 0; j < 4; ++j)
        bfr[j] = *(const s16x8*)(&Bs[(wn + j * 16 + ln) * LDA + ks * 32 + quad * 8]);
#pragma unroll
      for (int i = 0; i < 4; ++i)
#pragma unroll
        for (int j = 0; j < 4; ++j)
          acc[i][j] = __builtin_amdgcn_mfma_f32_16x16x32_bf16(af[i], bfr[j], acc[i][j], 0, 0, 0);
    }
    __syncthreads();
  }

#pragma unroll
  for (int j = 0; j < 4; ++j) {
    int gn = n0 + wn + j * 16 + ln;
    bool isV = (gn >= 2048);
    int e = isV ? (gn - 2048) : (gn & 1023);
    int h = e >> 6, d = e & 63;
    float inv = __expf(-0.2878231366f * (float)(d >> 1));
#pragma unroll
    for (int i = 0; i < 4; ++i) {
      int gmb = m0 + wm + i * 16 + quad * 4;
#pragma unroll
      for (int r = 0; r < 4; ++r) {
        float val = acc[i][j][r];
        float part = __shfl_xor(val, 1, 64);
        int m = gmb + r;
        int b = m >> 11, s = m & 2047;
        if (!isV) {
          float pos = (float)tok[s];
          float ang = pos * inv;
          float sn, cs;
          __sincosf(ang, &sn, &cs);
          float x0 = (d & 1) ? part : val;
          float x1 = (d & 1) ? val : part;
          float y = (d & 1) ? (x0 * sn + x1 * cs) : (x0 * cs - x1 * sn);
          unsigned short* dst = (gn < 1024) ? Qo : Ko;
          dst[(((size_t)b * 16 + h) * 2048 + s) * 64 + d] = f2b(y);
        } else {
          Vt[(((size_t)b * 16 + h) * 64 + d) * 2048 + s] = f2b(val);
        }
      }
    }
  }
}

// ---------------------------------------------------------------- split-K flash attention (partial)
// grid (32 qtiles, 4 kchunks, 32 bh), block 128 = 2 waves x 32 q-rows.
// Each block handles k in [c*512, min(c*512+512, qtile_end)); writes unnormalized
// O^T (bf16) + per-row (m,l) (f32) partials. Barrier-free, LDS-free.
#define CHUNK 512
__global__ __launch_bounds__(128) void attn_partial(
    const unsigned short* __restrict__ Q,
    const unsigned short* __restrict__ K,
    const unsigned short* __restrict__ Vt,
    unsigned short* __restrict__ Opart,
    float2* __restrict__ ML) {
  const int qt = blockIdx.x;
  const int c  = blockIdx.y;
  const int bh = blockIdx.z;
  const int kbeg = c * CHUNK;
  const int qend = qt * 64 + 64;
  if (kbeg >= qend) return;                 // inactive chunk
  const int khi = min(kbeg + CHUNK, qend);

  const int tid = threadIdx.x;
  const int w = tid >> 6, lane = tid & 63;
  const int ln = lane & 15, quad = lane >> 4;
  const int qb = qt * 64 + w * 32;

  const unsigned short* Qb = Q + (size_t)bh * 2048 * 64;
  const unsigned short* Kb = K + (size_t)bh * 2048 * 64;
  const unsigned short* Vb = Vt + (size_t)bh * 64 * 2048;

  s16x8 bq[2][2];
#pragma unroll
  for (int u = 0; u < 2; ++u)
#pragma unroll
    for (int hh = 0; hh < 2; ++hh)
      bq[u][hh] = *(const s16x8*)(&Qb[(size_t)(qb + u * 16 + ln) * 64 + hh * 32 + quad * 8]);

  const f32x4 zero = {0.f, 0.f, 0.f, 0.f};
  f32x4 o[2][4];
#pragma unroll
  for (int u = 0; u < 2; ++u)
#pragma unroll
    for (int j = 0; j < 4; ++j) o[u][j] = zero;
  float m_i[2] = {-3e38f, -3e38f};
  float l_i[2] = {0.f, 0.f};

  for (int k0 = kbeg; k0 < khi; k0 += 64) {
    s16x8 ka[4][2];
#pragma unroll
    for (int t = 0; t < 4; ++t)
#pragma unroll
      for (int hh = 0; hh < 2; ++hh)
        ka[t][hh] = *(const s16x8*)(&Kb[(size_t)(k0 + t * 16 + ln) * 64 + hh * 32 + quad * 8]);
    s16x8 va[4][2];
#pragma unroll
    for (int j = 0; j < 4; ++j)
#pragma unroll
      for (int hh = 0; hh < 2; ++hh)
        va[j][hh] = *(const s16x8*)(&Vb[(size_t)(j * 16 + ln) * 2048 + k0 + hh * 32 + quad * 8]);

#pragma unroll
    for (int u = 0; u < 2; ++u) {
      const int q = qb + u * 16 + ln;
      f32x4 st[4];
#pragma unroll
      for (int t = 0; t < 4; ++t) {
        f32x4 s = __builtin_amdgcn_mfma_f32_16x16x32_bf16(ka[t][0], bq[u][0], zero, 0, 0, 0);
        st[t] = __builtin_amdgcn_mfma_f32_16x16x32_bf16(ka[t][1], bq[u][1], s, 0, 0, 0);
      }
      float lm = -3e38f;
#pragma unroll
      for (int t = 0; t < 4; ++t)
#pragma unroll
        for (int r = 0; r < 4; ++r) {
          int kk = k0 + t * 16 + quad * 4 + r;
          float v = st[t][r] * 0.125f;
          v = (kk > q) ? -3e38f : v;
          st[t][r] = v;
          lm = fmaxf(lm, v);
        }
      lm = fmaxf(lm, __shfl_xor(lm, 16, 64));
      lm = fmaxf(lm, __shfl_xor(lm, 32, 64));
      float mn = fmaxf(m_i[u], lm);
      float al = __expf(m_i[u] - mn);
      float rs = 0.f;
#pragma unroll
      for (int t = 0; t < 4; ++t)
#pragma unroll
        for (int r = 0; r < 4; ++r) {
          float p = __expf(st[t][r] - mn);
          st[t][r] = p;
          rs += p;
        }
      rs += __shfl_xor(rs, 16, 64);
      rs += __shfl_xor(rs, 32, 64);
      m_i[u] = mn;
      l_i[u] = l_i[u] * al + rs;
#pragma unroll
      for (int j = 0; j < 4; ++j) o[u][j] *= al;
      unsigned int pk[4][2];
#pragma unroll
      for (int t = 0; t < 4; ++t) {
        pk[t][0] = pkbf(st[t][0], st[t][1]);
        pk[t][1] = pkbf(st[t][2], st[t][3]);
      }
#pragma unroll
      for (int hh = 0; hh < 2; ++hh) {
        int bi[4];
#pragma unroll
        for (int v = 0; v < 4; ++v) {
          int src = ln + 16 * ((quad & 1) * 2 + (v >> 1));
          int lo = __shfl((int)pk[2 * hh][v & 1], src, 64);
          int hi = __shfl((int)pk[2 * hh + 1][v & 1], src, 64);
          bi[v] = (quad < 2) ? lo : hi;
        }
        s16x8 pb = *(s16x8*)bi;
#pragma unroll
        for (int j = 0; j < 4; ++j)
          o[u][j] = __builtin_amdgcn_mfma_f32_16x16x32_bf16(va[j][hh], pb, o[u][j], 0, 0, 0);
      }
    }
  }
  // epilogue: unnormalized partials
#pragma unroll
  for (int u = 0; u < 2; ++u) {
    int s = qb + u * 16 + ln;
    size_t row = ((size_t)bh * 4 + c) * 2048 + s;
    if (quad == 0) ML[row] = make_float2(m_i[u], l_i[u]);
    size_t base = row * 64;
#pragma unroll
    for (int j = 0; j < 4; ++j) {
      ushort4 o4;
      o4.x = f2b(o[u][j][0]);
      o4.y = f2b(o[u][j][1]);
      o4.z = f2b(o[u][j][2]);
      o4.w = f2b(o[u][j][3]);
      *(ushort4*)(&Opart[base + j * 16 + quad * 4]) = o4;
    }
  }
}

// ---------------------------------------------------------------- merge partials -> Ab
// thread = (bh, q, 8-d group). 2048 blocks x 256.
__global__ __launch_bounds__(256) void attn_merge(
    const unsigned short* __restrict__ Opart,
    const float2* __restrict__ ML,
    unsigned short* __restrict__ Ao) {
  int idx = blockIdx.x * 256 + threadIdx.x;
  int d0 = (idx & 7) * 8;
  int q  = (idx >> 3) & 2047;
  int bh = idx >> 14;
  int qt = q >> 6;
  int nc = (qt + 8) >> 3;  // ceil((qt+1)/8)

  float m_c[4], l_c[4];
  float M = -3e38f;
  for (int c = 0; c < nc; ++c) {
    float2 ml = ML[((size_t)bh * 4 + c) * 2048 + q];
    m_c[c] = ml.x; l_c[c] = ml.y;
    M = fmaxf(M, ml.x);
  }
  float acc[8] = {0, 0, 0, 0, 0, 0, 0, 0};
  float L = 0.f;
  for (int c = 0; c < nc; ++c) {
    float wc = __expf(m_c[c] - M);
    L += wc * l_c[c];
    const ushort4* p = (const ushort4*)(Opart + (((size_t)bh * 4 + c) * 2048 + q) * 64 + d0);
    ushort4 a = p[0], bvec = p[1];
    acc[0] += wc * b2f(a.x); acc[1] += wc * b2f(a.y);
    acc[2] += wc * b2f(a.z); acc[3] += wc * b2f(a.w);
    acc[4] += wc * b2f(bvec.x); acc[5] += wc * b2f(bvec.y);
    acc[6] += wc * b2f(bvec.z); acc[7] += wc * b2f(bvec.w);
  }
  float invL = 1.0f / L;
  int b = bh >> 4, h = bh & 15;
  unsigned short* dst = Ao + ((size_t)b * 2048 + q) * 1024 + h * 64 + d0;
  ushort4 o0, o1;
  o0.x = f2b(acc[0] * invL); o0.y = f2b(acc[1] * invL);
  o0.z = f2b(acc[2] * invL); o0.w = f2b(acc[3] * invL);
  o1.x = f2b(acc[4] * invL); o1.y = f2b(acc[5] * invL);
  o1.z = f2b(acc[6] * invL); o1.w = f2b(acc[7] * invL);
  ((ushort4*)dst)[0] = o0;
  ((ushort4*)dst)[1] = o1;
}

// ---------------------------------------------------------------- output projection GEMM
__global__ __launch_bounds__(256) void gemm_out(
    const unsigned short* __restrict__ A,
    const unsigned short* __restrict__ Bt,
    float* __restrict__ out) {
  __shared__ unsigned short As[BM * LDA];
  __shared__ unsigned short Bs[BN * LDA];
  const int tid = threadIdx.x;
  const int m0 = blockIdx.x * BM;
  const int n0 = blockIdx.y * BN;
  const int w = tid >> 6, lane = tid & 63;
  const int ln = lane & 15, quad = lane >> 4;
  const int wm = (w >> 1) * 64, wn = (w & 1) * 64;

  const f32x4 zero = {0.f, 0.f, 0.f, 0.f};
  f32x4 acc[4][4];
#pragma unroll
  for (int i = 0; i < 4; ++i)
#pragma unroll
    for (int j = 0; j < 4; ++j) acc[i][j] = zero;

  for (int kb = 0; kb < KDIM / BK; ++kb) {
#pragma unroll
    for (int it = 0; it < 4; ++it) {
      int c = tid + it * 256;
      int row = c >> 3;
      int col = (c & 7) << 3;
      *(uint4*)(&As[row * LDA + col]) = *(const uint4*)(&A[(size_t)(m0 + row) * KDIM + kb * BK + col]);
      *(uint4*)(&Bs[row * LDA + col]) = *(const uint4*)(&Bt[(size_t)(n0 + row) * KDIM + kb * BK + col]);
    }
    __syncthreads();
#pragma unroll
    for (int ks = 0; ks < 2; ++ks) {
      s16x8 af[4], bfr[4];
#pragma unroll
      for (int i = 0; i < 4; ++i)
        af[i] = *(const s16x8*)(&As[(wm + i * 16 + ln) * LDA + ks * 32 + quad * 8]);
#pragma unroll
      for (int j = 0; j < 4; ++j)
        bfr[j] = *(const s16x8*)(&Bs[(wn + j * 16 + ln) * LDA + ks * 32 + quad * 8]);
#pragma unroll
      for (int i = 0; i < 4; ++i)
#pragma unroll
        for (int j = 0; j < 4; ++j)
          acc[i][j] = __builtin_amdgcn_mfma_f32_16x16x32_bf16(af[i], bfr[j], acc[i][j], 0, 0, 0);
    }
    __syncthreads();
  }
#pragma unroll
  for (int i = 0; i < 4; ++i) {
    int gmb = m0 + wm + i * 16 + quad * 4;
#pragma unroll
    for (int j = 0; j < 4; ++j) {
      int gn = n0 + wn + j * 16 + ln;
#pragma unroll
      for (int r = 0; r < 4; ++r)
        out[(size_t)(gmb + r) * 1024 + gn] = acc[i][j][r];
    }
  }
}

// ---------------------------------------------------------------- launch
extern "C" void kernel_launch(void* const* d_in, const int* in_sizes, int n_in,
                              void* d_out, int out_size, void* d_ws, size_t ws_size,
                              hipStream_t stream) {
  const float* x  = (const float*)d_in[0];
  const float* Wq = (const float*)d_in[1];
  const float* Wk = (const float*)d_in[2];
  const float* Wv = (const float*)d_in[3];
  const float* Wo = (const float*)d_in[4];
  const int* tok  = (const int*)d_in[5];
  float* out = (float*)d_out;

  char* ws = (char*)d_ws;
  unsigned short* xb    = (unsigned short*)(ws);
  unsigned short* Wcat  = (unsigned short*)(ws + (8ull  << 20));
  unsigned short* Wob   = (unsigned short*)(ws + (14ull << 20));
  unsigned short* Qb    = (unsigned short*)(ws + (16ull << 20));
  unsigned short* Kb    = (unsigned short*)(ws + (24ull << 20));
  unsigned short* Vtb   = (unsigned short*)(ws + (32ull << 20));
  unsigned short* Ab    = (unsigned short*)(ws + (40ull << 20));
  unsigned short* Opart = (unsigned short*)(ws + (48ull << 20));  // 33.6 MB: (bh,4,2048,64) bf16
  float2*         ML    = (float2*)        (ws + (82ull << 20));  // 4.2 MB: (bh,4,2048) f32x2

  cast_kernel<<<dim3(4096), dim3(256), 0, stream>>>(x,  xb,   1048576);
  cast_kernel<<<dim3(1024), dim3(256), 0, stream>>>(Wq, Wcat,            262144);
  cast_kernel<<<dim3(1024), dim3(256), 0, stream>>>(Wk, Wcat + (1u<<20), 262144);
  cast_kernel<<<dim3(1024), dim3(256), 0, stream>>>(Wv, Wcat + (2u<<20), 262144);
  cast_kernel<<<dim3(1024), dim3(256), 0, stream>>>(Wo, Wob,             262144);

  gemm_qkv<<<dim3(32, 24), dim3(256), 0, stream>>>(xb, Wcat, tok, Qb, Kb, Vtb);
  attn_partial<<<dim3(32, 4, 32), dim3(128), 0, stream>>>(Qb, Kb, Vtb, Opart, ML);
  attn_merge<<<dim3(2048), dim3(256), 0, stream>>>(Opart, ML, Ab);
  gemm_out<<<dim3(32, 8), dim3(256), 0, stream>>>(Ab, Wob, out);
}

// Round 4
// 222.773 us; speedup vs baseline: 1.3529x; 1.3529x over previous
//
#include <hip/hip_runtime.h>
#include <hip/hip_bf16.h>

typedef __attribute__((ext_vector_type(8))) short s16x8;
typedef __attribute__((ext_vector_type(4))) float f32x4;

__device__ __forceinline__ unsigned short f2b(float x) {
  unsigned int u = __float_as_uint(x);
  u = (u + 0x7fffu + ((u >> 16) & 1u)) >> 16;
  return (unsigned short)u;
}

__device__ __forceinline__ unsigned int pkbf(float a, float b) {
  return (unsigned int)f2b(a) | ((unsigned int)f2b(b) << 16);
}

__device__ __forceinline__ float b2f(unsigned short u) {
  return __uint_as_float((unsigned int)u << 16);
}

// async 16B/lane global->LDS (lane i lands at lds + i*16)
__device__ __forceinline__ void gl2lds16(const unsigned short* g, unsigned short* lds) {
  __builtin_amdgcn_global_load_lds(
      (const __attribute__((address_space(1))) unsigned int*)g,
      (__attribute__((address_space(3))) unsigned int*)lds, 16, 0, 0);
}

// ---------------------------------------------------------------- fused cast fp32 -> bf16
// dst layout: xb (1048576 f4) | Wq | Wk | Wv | Wo (262144 f4 each), contiguous.
__global__ __launch_bounds__(256) void cast_all(
    const float* __restrict__ x,  const float* __restrict__ Wq,
    const float* __restrict__ Wk, const float* __restrict__ Wv,
    const float* __restrict__ Wo, unsigned short* __restrict__ dst) {
  int i = blockIdx.x * 256 + threadIdx.x;
  const float* src;
  int off;
  if (i < 1048576) { src = x; off = i; }
  else {
    int j = i - 1048576;
    int seg = j >> 18;
    off = j & 262143;
    src = (seg == 0) ? Wq : (seg == 1) ? Wk : (seg == 2) ? Wv : Wo;
  }
  const float4 v = ((const float4*)src)[off];
  ushort4 o;
  o.x = f2b(v.x); o.y = f2b(v.y); o.z = f2b(v.z); o.w = f2b(v.w);
  ((ushort4*)dst)[i] = o;
}

#define BM 128
#define BN 128
#define BK 64
#define LDA 72
#define KDIM 1024

// ---------------------------------------------------------------- QKV GEMM + fused RoPE
__global__ __launch_bounds__(256) void gemm_qkv(
    const unsigned short* __restrict__ A,
    const unsigned short* __restrict__ Bt,
    const int* __restrict__ tok,
    unsigned short* __restrict__ Qo,
    unsigned short* __restrict__ Ko,
    unsigned short* __restrict__ Vt) {
  __shared__ unsigned short As[BM * LDA];
  __shared__ unsigned short Bs[BN * LDA];
  const int tid = threadIdx.x;
  const int m0 = blockIdx.x * BM;
  const int n0 = blockIdx.y * BN;
  const int w = tid >> 6, lane = tid & 63;
  const int ln = lane & 15, quad = lane >> 4;
  const int wm = (w >> 1) * 64, wn = (w & 1) * 64;

  const f32x4 zero = {0.f, 0.f, 0.f, 0.f};
  f32x4 acc[4][4];
#pragma unroll
  for (int i = 0; i < 4; ++i)
#pragma unroll
    for (int j = 0; j < 4; ++j) acc[i][j] = zero;

  for (int kb = 0; kb < KDIM / BK; ++kb) {
#pragma unroll
    for (int it = 0; it < 4; ++it) {
      int c = tid + it * 256;
      int row = c >> 3;
      int col = (c & 7) << 3;
      *(uint4*)(&As[row * LDA + col]) = *(const uint4*)(&A[(size_t)(m0 + row) * KDIM + kb * BK + col]);
      *(uint4*)(&Bs[row * LDA + col]) = *(const uint4*)(&Bt[(size_t)(n0 + row) * KDIM + kb * BK + col]);
    }
    __syncthreads();
#pragma unroll
    for (int ks = 0; ks < 2; ++ks) {
      s16x8 af[4], bfr[4];
#pragma unroll
      for (int i = 0; i < 4; ++i)
        af[i] = *(const s16x8*)(&As[(wm + i * 16 + ln) * LDA + ks * 32 + quad * 8]);
#pragma unroll
      for (int j = 0; j < 4; ++j)
        bfr[j] = *(const s16x8*)(&Bs[(wn + j * 16 + ln) * LDA + ks * 32 + quad * 8]);
#pragma unroll
      for (int i = 0; i < 4; ++i)
#pragma unroll
        for (int j = 0; j < 4; ++j)
          acc[i][j] = __builtin_amdgcn_mfma_f32_16x16x32_bf16(af[i], bfr[j], acc[i][j], 0, 0, 0);
    }
    __syncthreads();
  }

#pragma unroll
  for (int j = 0; j < 4; ++j) {
    int gn = n0 + wn + j * 16 + ln;
    bool isV = (gn >= 2048);
    int e = isV ? (gn - 2048) : (gn & 1023);
    int h = e >> 6, d = e & 63;
    float inv = __expf(-0.2878231366f * (float)(d >> 1));
#pragma unroll
    for (int i = 0; i < 4; ++i) {
      int gmb = m0 + wm + i * 16 + quad * 4;
#pragma unroll
      for (int r = 0; r < 4; ++r) {
        float val = acc[i][j][r];
        float part = __shfl_xor(val, 1, 64);
        int m = gmb + r;
        int b = m >> 11, s = m & 2047;
        if (!isV) {
          float pos = (float)tok[s];
          float ang = pos * inv;
          float sn, cs;
          __sincosf(ang, &sn, &cs);
          float x0 = (d & 1) ? part : val;
          float x1 = (d & 1) ? val : part;
          float y = (d & 1) ? (x0 * sn + x1 * cs) : (x0 * cs - x1 * sn);
          unsigned short* dst = (gn < 1024) ? Qo : Ko;
          dst[(((size_t)b * 16 + h) * 2048 + s) * 64 + d] = f2b(y);
        } else {
          Vt[(((size_t)b * 16 + h) * 64 + d) * 2048 + s] = f2b(val);
        }
      }
    }
  }
}

// ---------------------------------------------------------------- split-K flash attention (LDS-staged)
// Block = 256 thr = 4 waves, 128 q; item = (bh, qh 128-q tile, 512-k chunk).
// K/V tiles staged via coalesced global_load_lds with XOR granule swizzle
// (LDS[r][g] = global[r][g ^ (r&7)]), fragments via ds_read_b128.
__global__ __launch_bounds__(256, 3) void attn_partial(
    const unsigned short* __restrict__ Q,
    const unsigned short* __restrict__ K,
    const unsigned short* __restrict__ Vt,
    unsigned short* __restrict__ Opart,
    float2* __restrict__ ML) {
  __shared__ unsigned short Ks[64 * 64];   // [k-row][d], 128 B rows, swizzled
  __shared__ unsigned short Vs[64 * 64];   // [d-row][k], 128 B rows, swizzled
  __shared__ unsigned short Pt[4][16 * 72];  // per-wave P scratch [q][k], stride 72

  // decode work item (heavy 8-tile chunks first; grid = 1280)
  int idx = blockIdx.x;
  int bh, c, qh;
  if (idx < 896) {
    bh = idx / 28;
    int s = idx % 28;
    if (s < 13)      { c = 0; qh = 3 + s; }
    else if (s < 22) { c = 1; qh = 7 + (s - 13); }
    else if (s < 27) { c = 2; qh = 11 + (s - 22); }
    else             { c = 3; qh = 15; }
  } else {
    int j = idx - 896;
    bh = j / 12;
    int s = j % 12;
    int wt = s >> 2;          // 0,1,2 -> 6,4,2 tiles
    c = s & 3;
    qh = 4 * c + 2 - wt;
  }
  const int kbeg = c * 512;
  const int khi = min(kbeg + 512, qh * 128 + 128);

  const int tid = threadIdx.x;
  const int w = tid >> 6, lane = tid & 63;
  const int ln = lane & 15, quad = lane >> 4;
  const int qb = qh * 128 + w * 32;

  const unsigned short* Qb = Q + (size_t)bh * 2048 * 64;
  const unsigned short* Kb = K + (size_t)bh * 2048 * 64;
  const unsigned short* Vb = Vt + (size_t)bh * 64 * 2048;

  // staging lane mapping: lane -> (row r, granule g); fetch swizzled granule
  const int srow = w * 16 + (lane >> 3);   // rows srow, srow+8
  const int sg = (lane & 7) ^ (srow & 7);  // swizzled global granule (srow+8 same low bits)

  // Q as PV^T B-operand frags (per 16-q subtile u)
  s16x8 bq[2][2];
#pragma unroll
  for (int u = 0; u < 2; ++u)
#pragma unroll
    for (int hh = 0; hh < 2; ++hh)
      bq[u][hh] = *(const s16x8*)(&Qb[(size_t)(qb + u * 16 + ln) * 64 + hh * 32 + quad * 8]);

  const f32x4 zero = {0.f, 0.f, 0.f, 0.f};
  f32x4 o[2][4];
#pragma unroll
  for (int u = 0; u < 2; ++u)
#pragma unroll
    for (int j = 0; j < 4; ++j) o[u][j] = zero;
  float m_i[2] = {-3e38f, -3e38f};
  float l_i[2] = {0.f, 0.f};

  const int rdsw = ((ln & 7) * 8);  // read-swizzle helper (granule xor, in shorts)

  for (int k0 = kbeg; k0 < khi; k0 += 64) {
    __syncthreads();  // previous tile fully consumed by all waves
    // stage K rows [k0+srow(+8)] and V^T rows [srow(+8)] cols [k0,k0+64)
    gl2lds16(Kb + (size_t)(k0 + srow) * 64 + sg * 8,       &Ks[(w * 16) * 64]);
    gl2lds16(Kb + (size_t)(k0 + srow + 8) * 64 + sg * 8,   &Ks[(w * 16 + 8) * 64]);
    gl2lds16(Vb + (size_t)srow * 2048 + k0 + sg * 8,       &Vs[(w * 16) * 64]);
    gl2lds16(Vb + (size_t)(srow + 8) * 2048 + k0 + sg * 8, &Vs[(w * 16 + 8) * 64]);
    __syncthreads();  // drains vmcnt: staging visible

    // K fragments from LDS (shared by both u)
    s16x8 ka[4][2];
#pragma unroll
    for (int t = 0; t < 4; ++t)
#pragma unroll
      for (int hh = 0; hh < 2; ++hh)
        ka[t][hh] = *(const s16x8*)(&Ks[(t * 16 + ln) * 64 + (((hh * 4 + quad) * 8) ^ rdsw)]);

#pragma unroll
    for (int u = 0; u < 2; ++u) {
      const int q = qb + u * 16 + ln;
      f32x4 st[4];
#pragma unroll
      for (int t = 0; t < 4; ++t) {
        f32x4 s = __builtin_amdgcn_mfma_f32_16x16x32_bf16(ka[t][0], bq[u][0], zero, 0, 0, 0);
        st[t] = __builtin_amdgcn_mfma_f32_16x16x32_bf16(ka[t][1], bq[u][1], s, 0, 0, 0);
      }
      float lm = -3e38f;
#pragma unroll
      for (int t = 0; t < 4; ++t)
#pragma unroll
        for (int r = 0; r < 4; ++r) {
          int kk = k0 + t * 16 + quad * 4 + r;
          float v = st[t][r] * 0.125f;
          v = (kk > q) ? -3e38f : v;
          st[t][r] = v;
          lm = fmaxf(lm, v);
        }
      lm = fmaxf(lm, __shfl_xor(lm, 16, 64));
      lm = fmaxf(lm, __shfl_xor(lm, 32, 64));
      float mn = fmaxf(m_i[u], lm);
      float al = __expf(m_i[u] - mn);
      float rs = 0.f;
#pragma unroll
      for (int t = 0; t < 4; ++t)
#pragma unroll
        for (int r = 0; r < 4; ++r) {
          float p = __expf(st[t][r] - mn);
          st[t][r] = p;
          rs += p;
        }
      rs += __shfl_xor(rs, 16, 64);
      rs += __shfl_xor(rs, 32, 64);
      m_i[u] = mn;
      l_i[u] = l_i[u] * al + rs;
#pragma unroll
      for (int j = 0; j < 4; ++j) o[u][j] *= al;

      // P transpose via per-wave LDS scratch: write P[q=ln][k], read B-frags.
#pragma unroll
      for (int t = 0; t < 4; ++t) {
        uint2 pv;
        pv.x = pkbf(st[t][0], st[t][1]);
        pv.y = pkbf(st[t][2], st[t][3]);
        *(uint2*)(&Pt[w][ln * 72 + t * 16 + quad * 4]) = pv;
      }
      __builtin_amdgcn_wave_barrier();  // keep write->read order (DS pipe is per-wave in-order)
#pragma unroll
      for (int hh = 0; hh < 2; ++hh) {
        s16x8 pb = *(const s16x8*)(&Pt[w][ln * 72 + hh * 32 + quad * 8]);
#pragma unroll
        for (int j = 0; j < 4; ++j) {
          s16x8 va = *(const s16x8*)(&Vs[(j * 16 + ln) * 64 + (((hh * 4 + quad) * 8) ^ rdsw)]);
          o[u][j] = __builtin_amdgcn_mfma_f32_16x16x32_bf16(va, pb, o[u][j], 0, 0, 0);
        }
      }
      __builtin_amdgcn_wave_barrier();  // reads done before next u overwrites Pt
    }
  }

  // epilogue: unnormalized partials
#pragma unroll
  for (int u = 0; u < 2; ++u) {
    int s = qb + u * 16 + ln;
    size_t row = ((size_t)bh * 4 + c) * 2048 + s;
    if (quad == 0) ML[row] = make_float2(m_i[u], l_i[u]);
    size_t base = row * 64;
#pragma unroll
    for (int j = 0; j < 4; ++j) {
      ushort4 o4;
      o4.x = f2b(o[u][j][0]);
      o4.y = f2b(o[u][j][1]);
      o4.z = f2b(o[u][j][2]);
      o4.w = f2b(o[u][j][3]);
      *(ushort4*)(&Opart[base + j * 16 + quad * 4]) = o4;
    }
  }
}

// ---------------------------------------------------------------- merge partials -> Ab
__global__ __launch_bounds__(256) void attn_merge(
    const unsigned short* __restrict__ Opart,
    const float2* __restrict__ ML,
    unsigned short* __restrict__ Ao) {
  int idx = blockIdx.x * 256 + threadIdx.x;
  int d0 = (idx & 7) * 8;
  int q  = (idx >> 3) & 2047;
  int bh = idx >> 14;
  int nc = (q >> 9) + 1;

  float m_c[4], l_c[4];
  float M = -3e38f;
  for (int c = 0; c < nc; ++c) {
    float2 ml = ML[((size_t)bh * 4 + c) * 2048 + q];
    m_c[c] = ml.x; l_c[c] = ml.y;
    M = fmaxf(M, ml.x);
  }
  float acc[8] = {0, 0, 0, 0, 0, 0, 0, 0};
  float L = 0.f;
  for (int c = 0; c < nc; ++c) {
    float wc = __expf(m_c[c] - M);
    L += wc * l_c[c];
    const ushort4* p = (const ushort4*)(Opart + (((size_t)bh * 4 + c) * 2048 + q) * 64 + d0);
    ushort4 a = p[0], bvec = p[1];
    acc[0] += wc * b2f(a.x); acc[1] += wc * b2f(a.y);
    acc[2] += wc * b2f(a.z); acc[3] += wc * b2f(a.w);
    acc[4] += wc * b2f(bvec.x); acc[5] += wc * b2f(bvec.y);
    acc[6] += wc * b2f(bvec.z); acc[7] += wc * b2f(bvec.w);
  }
  float invL = 1.0f / L;
  int b = bh >> 4, h = bh & 15;
  unsigned short* dst = Ao + ((size_t)b * 2048 + q) * 1024 + h * 64 + d0;
  ushort4 o0, o1;
  o0.x = f2b(acc[0] * invL); o0.y = f2b(acc[1] * invL);
  o0.z = f2b(acc[2] * invL); o0.w = f2b(acc[3] * invL);
  o1.x = f2b(acc[4] * invL); o1.y = f2b(acc[5] * invL);
  o1.z = f2b(acc[6] * invL); o1.w = f2b(acc[7] * invL);
  ((ushort4*)dst)[0] = o0;
  ((ushort4*)dst)[1] = o1;
}

// ---------------------------------------------------------------- output projection GEMM
__global__ __launch_bounds__(256) void gemm_out(
    const unsigned short* __restrict__ A,
    const unsigned short* __restrict__ Bt,
    float* __restrict__ out) {
  __shared__ unsigned short As[BM * LDA];
  __shared__ unsigned short Bs[BN * LDA];
  const int tid = threadIdx.x;
  const int m0 = blockIdx.x * BM;
  const int n0 = blockIdx.y * BN;
  const int w = tid >> 6, lane = tid & 63;
  const int ln = lane & 15, quad = lane >> 4;
  const int wm = (w >> 1) * 64, wn = (w & 1) * 64;

  const f32x4 zero = {0.f, 0.f, 0.f, 0.f};
  f32x4 acc[4][4];
#pragma unroll
  for (int i = 0; i < 4; ++i)
#pragma unroll
    for (int j = 0; j < 4; ++j) acc[i][j] = zero;

  for (int kb = 0; kb < KDIM / BK; ++kb) {
#pragma unroll
    for (int it = 0; it < 4; ++it) {
      int c = tid + it * 256;
      int row = c >> 3;
      int col = (c & 7) << 3;
      *(uint4*)(&As[row * LDA + col]) = *(const uint4*)(&A[(size_t)(m0 + row) * KDIM + kb * BK + col]);
      *(uint4*)(&Bs[row * LDA + col]) = *(const uint4*)(&Bt[(size_t)(n0 + row) * KDIM + kb * BK + col]);
    }
    __syncthreads();
#pragma unroll
    for (int ks = 0; ks < 2; ++ks) {
      s16x8 af[4], bfr[4];
#pragma unroll
      for (int i = 0; i < 4; ++i)
        af[i] = *(const s16x8*)(&As[(wm + i * 16 + ln) * LDA + ks * 32 + quad * 8]);
#pragma unroll
      for (int j = 0; j < 4; ++j)
        bfr[j] = *(const s16x8*)(&Bs[(wn + j * 16 + ln) * LDA + ks * 32 + quad * 8]);
#pragma unroll
      for (int i = 0; i < 4; ++i)
#pragma unroll
        for (int j = 0; j < 4; ++j)
          acc[i][j] = __builtin_amdgcn_mfma_f32_16x16x32_bf16(af[i], bfr[j], acc[i][j], 0, 0, 0);
    }
    __syncthreads();
  }
#pragma unroll
  for (int i = 0; i < 4; ++i) {
    int gmb = m0 + wm + i * 16 + quad * 4;
#pragma unroll
    for (int j = 0; j < 4; ++j) {
      int gn = n0 + wn + j * 16 + ln;
#pragma unroll
      for (int r = 0; r < 4; ++r)
        out[(size_t)(gmb + r) * 1024 + gn] = acc[i][j][r];
    }
  }
}

// ---------------------------------------------------------------- launch
extern "C" void kernel_launch(void* const* d_in, const int* in_sizes, int n_in,
                              void* d_out, int out_size, void* d_ws, size_t ws_size,
                              hipStream_t stream) {
  const float* x  = (const float*)d_in[0];
  const float* Wq = (const float*)d_in[1];
  const float* Wk = (const float*)d_in[2];
  const float* Wv = (const float*)d_in[3];
  const float* Wo = (const float*)d_in[4];
  const int* tok  = (const int*)d_in[5];
  float* out = (float*)d_out;

  char* ws = (char*)d_ws;
  unsigned short* xb    = (unsigned short*)(ws);                  // 8 MB
  unsigned short* Wcat  = (unsigned short*)(ws + (8ull  << 20));  // 6 MB
  unsigned short* Wob   = (unsigned short*)(ws + (14ull << 20));  // 2 MB
  unsigned short* Qb    = (unsigned short*)(ws + (16ull << 20));  // 8 MB
  unsigned short* Kb    = (unsigned short*)(ws + (24ull << 20));  // 8 MB
  unsigned short* Vtb   = (unsigned short*)(ws + (32ull << 20));  // 8 MB
  unsigned short* Ab    = (unsigned short*)(ws + (40ull << 20));  // 8 MB
  unsigned short* Opart = (unsigned short*)(ws + (48ull << 20));  // 32 MB
  float2*         ML    = (float2*)        (ws + (80ull << 20));  // 2 MB

  cast_all<<<dim3(8192), dim3(256), 0, stream>>>(x, Wq, Wk, Wv, Wo, xb);
  gemm_qkv<<<dim3(32, 24), dim3(256), 0, stream>>>(xb, Wcat, tok, Qb, Kb, Vtb);
  attn_partial<<<dim3(1280), dim3(256), 0, stream>>>(Qb, Kb, Vtb, Opart, ML);
  attn_merge<<<dim3(2048), dim3(256), 0, stream>>>(Opart, ML, Ab);
  gemm_out<<<dim3(32, 8), dim3(256), 0, stream>>>(Ab, Wob, out);
}